// Round 12
// baseline (136.079 us; speedup 1.0000x reference)
//
#include <hip/hip_runtime.h>
#include <hip/hip_bf16.h>

typedef _Float16 half8 __attribute__((ext_vector_type(8)));
typedef __fp16 fp16x2 __attribute__((ext_vector_type(2)));
typedef float f32x4 __attribute__((ext_vector_type(4)));

#define B_ 8
#define U_ 1024
#define N_ 2048
#define DIN 128
#define H_ 4
#define HD 32
#define S_ 3072
#define LOG2E 1.44269504f

// ---------------- phase 0: adjacency -> tiled global bitmasks ----------------
// mA[b][rt=r/16][t=c/32][r16=r%16] (A-dir: user rows x news cols, 64 tiles)
// mB[b][rt][t][r16]                (B-dir: news rows x user cols, 32 tiles)
// Layout puts the 16 row-words of one (rt,t) in one 64B line -> p2's per-tile
// mask read is a single broadcast dword load. One wave per (dir,b,row);
// iterations are independent (unroll 4) so ballot latency is hidden by 24K waves.
__global__ __launch_bounds__(256) void p0_kernel(
    const int* __restrict__ adj,
    unsigned int* __restrict__ mA, unsigned int* __restrict__ mB)
{
  const int task = blockIdx.x * 4 + (threadIdx.x >> 6);
  const int l = threadIdx.x & 63;
  const int* rowp;
  unsigned int* mOut;
  int iters;
  if (task < 8192) {                    // A-dir: b = task>>10, r = task&1023
    int b = task >> 10, r = task & 1023;
    rowp = adj + ((size_t)b * S_ + r) * S_ + U_;
    iters = 32;                         // 2048 cols
    mOut = mA + ((size_t)(b * 64 + (r >> 4)) * 64) * 16 + (r & 15);
  } else {                              // B-dir: b = t2>>11, r = t2&2047
    int t2 = task - 8192;
    int b = t2 >> 11, r = t2 & 2047;
    rowp = adj + ((size_t)b * S_ + U_ + r) * S_;
    iters = 16;                         // 1024 cols
    mOut = mB + ((size_t)(b * 128 + (r >> 4)) * 32) * 16 + (r & 15);
  }
  #pragma unroll 4
  for (int it = 0; it < iters; ++it) {
    int av = rowp[it * 64 + l];
    unsigned long long m = __ballot(av != 0);
    if (l == 0) {
      mOut[(2 * it) * 16]     = (unsigned int)m;         // word t = 2it
      mOut[(2 * it + 1) * 16] = (unsigned int)(m >> 32); // word t = 2it+1
    }
  }
}

// ---------------- phase 1: projections + e-vectors + tiled f16 V ----------------
// (unchanged from round 11) Head-parallel; row-side e raw (log2e-scaled);
// col-side e as (exp2(e), exp2(0.2e)) pairs -> p2 has no per-tile transcendentals.
__global__ __launch_bounds__(256) void p1_kernel(
    const float* __restrict__ uf, const float* __restrict__ nf,
    const float* __restrict__ Wu, const float* __restrict__ Wn,
    const float* __restrict__ a_un, const float* __restrict__ a_nu,
    _Float16* __restrict__ vtA, _Float16* __restrict__ vtB,
    float* __restrict__ eRowA, float2* __restrict__ eColA2,
    float* __restrict__ eRowB, float2* __restrict__ eColB2)
{
  __shared__ float fs[64][132];
  __shared__ float WsT[32][132];
  __shared__ float qt[32][65];
  __shared__ float aAs[32], aBs[32];

  const int bid = blockIdx.x;
  const int tid = threadIdx.x;

  int b, rt, R, h;
  const float *feat, *W;
  _Float16* vt;
  float* eRaw;
  float2* ePair;
  bool part0raw;
  int aAoff, aBoff;
  const float *avA, *avB;
  if (bid < 512) {                       // users: 8b x 16rt x 4h
    h = bid & 3; int t2 = bid >> 2; b = t2 >> 4; rt = t2 & 15; R = U_;
    feat = uf; W = Wu; vt = vtB;
    eRaw = eRowA; ePair = eColB2; part0raw = true;
    avA = a_un; aAoff = 0;  avB = a_nu; aBoff = HD;
  } else {                               // news: 8b x 32rt x 4h
    int t3 = bid - 512;
    h = t3 & 3; int t2 = t3 >> 2; b = t2 >> 5; rt = t2 & 31; R = N_;
    feat = nf; W = Wn; vt = vtA;
    eRaw = eRowB; ePair = eColA2; part0raw = false;
    avA = a_un; aAoff = HD; avB = a_nu; aBoff = 0;
  }
  const int r0 = rt * 64;

  const float4* feat4 = (const float4*)(feat + ((size_t)b * R + r0) * DIN);
  #pragma unroll
  for (int i = 0; i < 8; ++i) {
    int f4 = tid + 256 * i;
    int row = f4 >> 5, c4 = f4 & 31;
    *(float4*)&fs[row][c4 * 4] = feat4[row * 32 + c4];
  }
  {
    const float4* W4 = (const float4*)(W + (size_t)h * DIN * HD);
    #pragma unroll
    for (int i = 0; i < 4; ++i) {
      int f4 = tid + 256 * i;
      int d = f4 >> 3, kc = f4 & 7;
      float4 v = W4[f4];
      WsT[kc * 4 + 0][d] = v.x;
      WsT[kc * 4 + 1][d] = v.y;
      WsT[kc * 4 + 2][d] = v.z;
      WsT[kc * 4 + 3][d] = v.w;
    }
    if (tid < 32) {
      aAs[tid] = avA[h * 64 + aAoff + tid];
      aBs[tid] = avB[h * 64 + aBoff + tid];
    }
  }
  __syncthreads();

  const int kk = tid & 15, uu = tid >> 4;
  {
    float acc0[4] = {0.f, 0.f, 0.f, 0.f}, acc1[4] = {0.f, 0.f, 0.f, 0.f};
    #pragma unroll 8
    for (int d = 0; d < DIN; d += 4) {
      float4 w0 = *(const float4*)&WsT[kk][d];
      float4 w1 = *(const float4*)&WsT[kk + 16][d];
      #pragma unroll
      for (int i = 0; i < 4; ++i) {
        float4 fv = *(const float4*)&fs[uu + 16 * i][d];
        acc0[i] = fmaf(fv.x, w0.x, acc0[i]); acc0[i] = fmaf(fv.y, w0.y, acc0[i]);
        acc0[i] = fmaf(fv.z, w0.z, acc0[i]); acc0[i] = fmaf(fv.w, w0.w, acc0[i]);
        acc1[i] = fmaf(fv.x, w1.x, acc1[i]); acc1[i] = fmaf(fv.y, w1.y, acc1[i]);
        acc1[i] = fmaf(fv.z, w1.z, acc1[i]); acc1[i] = fmaf(fv.w, w1.w, acc1[i]);
      }
    }
    #pragma unroll
    for (int i = 0; i < 4; ++i) {
      qt[kk][uu + 16 * i] = acc0[i];
      qt[kk + 16][uu + 16 * i] = acc1[i];
    }
  }
  __syncthreads();

  const int u2 = tid & 63, part = tid >> 6;
  {
    size_t vtbase = (size_t)(b * H_ + h) * (R * HD)
                  + (size_t)((r0 >> 5) + (u2 >> 5)) * (HD * 32) + (u2 & 31);
    #pragma unroll
    for (int jj = 0; jj < 8; ++jj) {
      int krow = part * 8 + jj;
      vt[vtbase + krow * 32] = (_Float16)qt[krow][u2];
    }
  }
  if (part < 2) {
    float a_ = 0.f;
    const float* av = (part == 0) ? aAs : aBs;
    #pragma unroll
    for (int k2 = 0; k2 < HD; ++k2)
      a_ = fmaf(qt[k2][u2], av[k2], a_);
    float e = a_ * LOG2E;
    size_t idx = (size_t)(b * H_ + h) * R + r0 + u2;
    bool raw = (part == 0) ? part0raw : !part0raw;
    if (raw) eRaw[idx] = e;
    else     ePair[idx] = make_float2(exp2f(e), exp2f(0.2f * e));
  }
}

// ---------------- phase 2: barrier-free fused masked-softmax GEMM ----------------
struct Tile { float4 e0, e1, e2, e3; half8 v0, v1; unsigned int m32; };

__device__ __forceinline__ Tile load_tile(
    int t, int cg, int row16,
    const float2* __restrict__ ecol2, const _Float16* __restrict__ vtb,
    const unsigned int* __restrict__ mT)
{
  Tile ti;
  const int cb = t * 32 + cg;
  const float4* ep = (const float4*)(ecol2 + cb);   // (E1,E2) pairs, broadcast/group
  ti.e0 = ep[0]; ti.e1 = ep[1]; ti.e2 = ep[2]; ti.e3 = ep[3];
  ti.v0 = *(const half8*)(vtb + t * (HD * 32) + row16 * 32 + cg);
  ti.v1 = *(const half8*)(vtb + t * (HD * 32) + (row16 + 16) * 32 + cg);
  ti.m32 = mT[t * 16 + row16];                      // one 64B line per wave-tile
  return ti;
}

__device__ __forceinline__ void compute_tile(
    const Tile& ti, int cg, float F1, float F2, float G, half8 ones,
    f32x4& acc0, f32x4& acc1, f32x4& accd)
{
  const unsigned int mb = ti.m32 >> cg;
  // w = mask ? (E1>G ? E1*F1 : E2*F2) : 0  — zero transcendentals in the loop.
  float wv[8];
  wv[0] = (mb & 1u)   ? (ti.e0.x > G ? ti.e0.x * F1 : ti.e0.y * F2) : 0.f;
  wv[1] = (mb & 2u)   ? (ti.e0.z > G ? ti.e0.z * F1 : ti.e0.w * F2) : 0.f;
  wv[2] = (mb & 4u)   ? (ti.e1.x > G ? ti.e1.x * F1 : ti.e1.y * F2) : 0.f;
  wv[3] = (mb & 8u)   ? (ti.e1.z > G ? ti.e1.z * F1 : ti.e1.w * F2) : 0.f;
  wv[4] = (mb & 16u)  ? (ti.e2.x > G ? ti.e2.x * F1 : ti.e2.y * F2) : 0.f;
  wv[5] = (mb & 32u)  ? (ti.e2.z > G ? ti.e2.z * F1 : ti.e2.w * F2) : 0.f;
  wv[6] = (mb & 64u)  ? (ti.e3.x > G ? ti.e3.x * F1 : ti.e3.y * F2) : 0.f;
  wv[7] = (mb & 128u) ? (ti.e3.z > G ? ti.e3.z * F1 : ti.e3.w * F2) : 0.f;
  union { fp16x2 h2[4]; half8 h8; } uw;
  uw.h2[0] = __builtin_amdgcn_cvt_pkrtz(wv[0], wv[1]);
  uw.h2[1] = __builtin_amdgcn_cvt_pkrtz(wv[2], wv[3]);
  uw.h2[2] = __builtin_amdgcn_cvt_pkrtz(wv[4], wv[5]);
  uw.h2[3] = __builtin_amdgcn_cvt_pkrtz(wv[6], wv[7]);
  half8 w = uw.h8;
  acc0 = __builtin_amdgcn_mfma_f32_16x16x32_f16(w, ti.v0, acc0, 0, 0, 0);
  acc1 = __builtin_amdgcn_mfma_f32_16x16x32_f16(w, ti.v1, acc1, 0, 0, 0);
  accd = __builtin_amdgcn_mfma_f32_16x16x32_f16(w, ones, accd, 0, 0, 0);
}

// 16 rows/block, wave = head, NO LDS, NO barriers: mask comes pre-packed from p0.
template<int RR, int CC>
__device__ __forceinline__ void p2_core(
    int b, int rt, int wave, int l,
    const unsigned int* __restrict__ mT, const _Float16* __restrict__ vt,
    const float* __restrict__ eRow, const float2* __restrict__ eCol2,
    const float* __restrict__ bias, float* __restrict__ out)
{
  const int h = wave;
  const int row16 = l & 15;
  const int cg = (l >> 4) << 3;
  const int r = rt * 16 + row16;
  const float eq = eRow[(size_t)(b * H_ + h) * RR + r];
  const float F1 = exp2f(eq), F2 = exp2f(0.2f * eq), G = exp2f(-eq);
  const float2* ecol2 = eCol2 + (size_t)(b * H_ + h) * CC;
  const _Float16* vtb = vt + (size_t)(b * H_ + h) * (CC * HD);

  f32x4 acc0 = {0.f,0.f,0.f,0.f}, acc1 = {0.f,0.f,0.f,0.f}, accd = {0.f,0.f,0.f,0.f};
  half8 ones = {(_Float16)1.f, (_Float16)1.f, (_Float16)1.f, (_Float16)1.f,
                (_Float16)1.f, (_Float16)1.f, (_Float16)1.f, (_Float16)1.f};

  constexpr int T = CC / 32;
  Tile cur = load_tile(0, cg, row16, ecol2, vtb, mT);
  #pragma unroll 2
  for (int t = 0; t < T - 1; ++t) {
    Tile nxt = load_tile(t + 1, cg, row16, ecol2, vtb, mT);
    compute_tile(cur, cg, F1, F2, G, ones, acc0, acc1, accd);
    cur = nxt;
  }
  compute_tile(cur, cg, F1, F2, G, ones, acc0, acc1, accd);

  const int colk = row16;
  const int rowbase = rt * 16 + ((l >> 4) << 2);
  #pragma unroll
  for (int q = 0; q < 4; ++q) {
    int orow = rowbase + q;
    size_t o = ((size_t)(b * H_ + h) * RR + orow) * 32 + colk;
    float den = accd[q];
    float v0 = acc0[q] / den + bias[q * 32 + colk];
    float v1 = acc1[q] / den + bias[q * 32 + colk + 16];
    out[o]      = v0 > 0.f ? v0 : 0.f;
    out[o + 16] = v1 > 0.f ? v1 : 0.f;
  }
}

__global__ __launch_bounds__(256, 4) void p2_kernel(
    const unsigned int* __restrict__ mA, const unsigned int* __restrict__ mB,
    const _Float16* __restrict__ vtA, const _Float16* __restrict__ vtB,
    const float* __restrict__ eRowA, const float2* __restrict__ eColA2,
    const float* __restrict__ eRowB, const float2* __restrict__ eColB2,
    const float* __restrict__ bu, const float* __restrict__ bn,
    float* __restrict__ out)
{
  const int tid = threadIdx.x;
  const int wave = tid >> 6, l = tid & 63;
  const int bid = blockIdx.x;
  if (bid < B_ * (U_ / 16)) {                     // 512 blocks, rt 0..63
    const int b = bid & 7, rt = bid >> 3;
    const unsigned int* mT = mA + ((size_t)(b * 64 + rt) * 64) * 16;
    p2_core<U_, N_>(b, rt, wave, l, mT, vtA, eRowA, eColA2, bu, out);
  } else {                                        // 1024 blocks, rt 0..127
    const int t2 = bid - B_ * (U_ / 16);
    const int b = t2 & 7, rt = t2 >> 3;
    const unsigned int* mT = mB + ((size_t)(b * 128 + rt) * 32) * 16;
    p2_core<N_, U_>(b, rt, wave, l, mT, vtB, eRowB, eColB2, bn,
                    out + (size_t)B_ * U_ * 128);
  }
}

extern "C" void kernel_launch(void* const* d_in, const int* in_sizes, int n_in,
                              void* d_out, int out_size, void* d_ws, size_t ws_size,
                              hipStream_t stream) {
  const float* uf  = (const float*)d_in[0];
  const float* nf  = (const float*)d_in[1];
  const int*   adj = (const int*)d_in[2];
  const float* Wu  = (const float*)d_in[3];
  const float* Wn  = (const float*)d_in[4];
  const float* aun = (const float*)d_in[5];
  const float* anu = (const float*)d_in[6];
  const float* bu  = (const float*)d_in[7];
  const float* bn  = (const float*)d_in[8];

  char* ws = (char*)d_ws;
  size_t off = 0;
  _Float16* vtA = (_Float16*)(ws + off); off += (size_t)B_ * H_ * HD * N_ * 2;  // 4 MB
  _Float16* vtB = (_Float16*)(ws + off); off += (size_t)B_ * H_ * HD * U_ * 2;  // 2 MB
  float*  eRowA  = (float*)(ws + off);  off += (size_t)B_ * H_ * U_ * 4;
  float2* eColA2 = (float2*)(ws + off); off += (size_t)B_ * H_ * N_ * 8;
  float*  eRowB  = (float*)(ws + off);  off += (size_t)B_ * H_ * N_ * 4;
  float2* eColB2 = (float2*)(ws + off); off += (size_t)B_ * H_ * U_ * 8;
  unsigned int* mA = (unsigned int*)(ws + off); off += (size_t)B_ * 64 * 64 * 16 * 4;  // 2 MB
  unsigned int* mB = (unsigned int*)(ws + off); off += (size_t)B_ * 128 * 32 * 16 * 4; // 2 MB
  (void)off; (void)ws_size; (void)in_sizes; (void)n_in; (void)out_size;        // ~12.2 MB

  p0_kernel<<<6144, 256, 0, stream>>>(adj, mA, mB);
  p1_kernel<<<512 + 1024, 256, 0, stream>>>(uf, nf, Wu, Wn, aun, anu,
                                            vtA, vtB, eRowA, eColA2, eRowB, eColB2);
  p2_kernel<<<B_ * (U_ / 16) + B_ * (N_ / 16), 256, 0, stream>>>(
      mA, mB, vtA, vtB, eRowA, eColA2, eRowB, eColB2, bu, bn, (float*)d_out);
}

// Round 13
// 122.260 us; speedup vs baseline: 1.1130x; 1.1130x over previous
//
#include <hip/hip_runtime.h>
#include <hip/hip_bf16.h>

typedef _Float16 half8 __attribute__((ext_vector_type(8)));
typedef __fp16 fp16x2 __attribute__((ext_vector_type(2)));
typedef float f32x4 __attribute__((ext_vector_type(4)));

#define B_ 8
#define U_ 1024
#define N_ 2048
#define DIN 128
#define H_ 4
#define HD 32
#define S_ 3072
#define LOG2E 1.44269504f
#define NU (B_ * U_ * 128)            // 1048576

// ---------------- phase 0: adjacency -> tiled global bitmasks (unchanged) ----------------
__global__ __launch_bounds__(256) void p0_kernel(
    const int* __restrict__ adj,
    unsigned int* __restrict__ mA, unsigned int* __restrict__ mB)
{
  const int task = blockIdx.x * 4 + (threadIdx.x >> 6);
  const int l = threadIdx.x & 63;
  const int* rowp;
  unsigned int* mOut;
  int iters;
  if (task < 8192) {                    // A-dir: user rows x news cols
    int b = task >> 10, r = task & 1023;
    rowp = adj + ((size_t)b * S_ + r) * S_ + U_;
    iters = 32;
    mOut = mA + ((size_t)(b * 64 + (r >> 4)) * 64) * 16 + (r & 15);
  } else {                              // B-dir: news rows x user cols
    int t2 = task - 8192;
    int b = t2 >> 11, r = t2 & 2047;
    rowp = adj + ((size_t)b * S_ + U_ + r) * S_;
    iters = 16;
    mOut = mB + ((size_t)(b * 128 + (r >> 4)) * 32) * 16 + (r & 15);
  }
  #pragma unroll 4
  for (int it = 0; it < iters; ++it) {
    int av = rowp[it * 64 + l];
    unsigned long long m = __ballot(av != 0);
    if (l == 0) {
      mOut[(2 * it) * 16]     = (unsigned int)m;
      mOut[(2 * it + 1) * 16] = (unsigned int)(m >> 32);
    }
  }
}

// ---------------- phase 1: projections + raw e + tiled f16 V ----------------
__global__ __launch_bounds__(256) void p1_kernel(
    const float* __restrict__ uf, const float* __restrict__ nf,
    const float* __restrict__ Wu, const float* __restrict__ Wn,
    const float* __restrict__ a_un, const float* __restrict__ a_nu,
    _Float16* __restrict__ vtA, _Float16* __restrict__ vtB,
    float* __restrict__ eRowA, float* __restrict__ eColA,
    float* __restrict__ eRowB, float* __restrict__ eColB)
{
  __shared__ float fs[64][132];
  __shared__ float WsT[32][132];
  __shared__ float qt[32][65];
  __shared__ float aAs[32], aBs[32];

  const int bid = blockIdx.x;
  const int tid = threadIdx.x;

  int b, rt, R, h;
  const float *feat, *W;
  _Float16* vt;
  float *eA, *eB;
  int aAoff, aBoff;
  const float *avA, *avB;
  if (bid < 512) {                       // users: 8b x 16rt x 4h
    h = bid & 3; int t2 = bid >> 2; b = t2 >> 4; rt = t2 & 15; R = U_;
    feat = uf; W = Wu; vt = vtB;
    eA = eRowA; eB = eColB;
    avA = a_un; aAoff = 0;  avB = a_nu; aBoff = HD;
  } else {                               // news: 8b x 32rt x 4h
    int t3 = bid - 512;
    h = t3 & 3; int t2 = t3 >> 2; b = t2 >> 5; rt = t2 & 31; R = N_;
    feat = nf; W = Wn; vt = vtA;
    eA = eColA; eB = eRowB;
    avA = a_un; aAoff = HD; avB = a_nu; aBoff = 0;
  }
  const int r0 = rt * 64;

  const float4* feat4 = (const float4*)(feat + ((size_t)b * R + r0) * DIN);
  #pragma unroll
  for (int i = 0; i < 8; ++i) {
    int f4 = tid + 256 * i;
    int row = f4 >> 5, c4 = f4 & 31;
    *(float4*)&fs[row][c4 * 4] = feat4[row * 32 + c4];
  }
  {
    const float4* W4 = (const float4*)(W + (size_t)h * DIN * HD);
    #pragma unroll
    for (int i = 0; i < 4; ++i) {
      int f4 = tid + 256 * i;
      int d = f4 >> 3, kc = f4 & 7;
      float4 v = W4[f4];
      WsT[kc * 4 + 0][d] = v.x;
      WsT[kc * 4 + 1][d] = v.y;
      WsT[kc * 4 + 2][d] = v.z;
      WsT[kc * 4 + 3][d] = v.w;
    }
    if (tid < 32) {
      aAs[tid] = avA[h * 64 + aAoff + tid];
      aBs[tid] = avB[h * 64 + aBoff + tid];
    }
  }
  __syncthreads();

  const int kk = tid & 15, uu = tid >> 4;
  {
    float acc0[4] = {0.f, 0.f, 0.f, 0.f}, acc1[4] = {0.f, 0.f, 0.f, 0.f};
    #pragma unroll 8
    for (int d = 0; d < DIN; d += 4) {
      float4 w0 = *(const float4*)&WsT[kk][d];
      float4 w1 = *(const float4*)&WsT[kk + 16][d];
      #pragma unroll
      for (int i = 0; i < 4; ++i) {
        float4 fv = *(const float4*)&fs[uu + 16 * i][d];
        acc0[i] = fmaf(fv.x, w0.x, acc0[i]); acc0[i] = fmaf(fv.y, w0.y, acc0[i]);
        acc0[i] = fmaf(fv.z, w0.z, acc0[i]); acc0[i] = fmaf(fv.w, w0.w, acc0[i]);
        acc1[i] = fmaf(fv.x, w1.x, acc1[i]); acc1[i] = fmaf(fv.y, w1.y, acc1[i]);
        acc1[i] = fmaf(fv.z, w1.z, acc1[i]); acc1[i] = fmaf(fv.w, w1.w, acc1[i]);
      }
    }
    #pragma unroll
    for (int i = 0; i < 4; ++i) {
      qt[kk][uu + 16 * i] = acc0[i];
      qt[kk + 16][uu + 16 * i] = acc1[i];
    }
  }
  __syncthreads();

  const int u2 = tid & 63, part = tid >> 6;
  {
    size_t vtbase = (size_t)(b * H_ + h) * (R * HD)
                  + (size_t)((r0 >> 5) + (u2 >> 5)) * (HD * 32) + (u2 & 31);
    #pragma unroll
    for (int jj = 0; jj < 8; ++jj) {
      int krow = part * 8 + jj;
      vt[vtbase + krow * 32] = (_Float16)qt[krow][u2];
    }
  }
  if (part < 2) {
    float a_ = 0.f;
    const float* av = (part == 0) ? aAs : aBs;
    #pragma unroll
    for (int k2 = 0; k2 < HD; ++k2)
      a_ = fmaf(qt[k2][u2], av[k2], a_);
    float* e = (part == 0) ? eA : eB;
    e[(size_t)(b * H_ + h) * R + r0 + u2] = a_ * LOG2E;  // raw, log2e-scaled
  }
}

// ---------------- phase 2: uniform-grid fused masked-softmax GEMM ----------------
// 2048 blocks = exactly 8/CU, ALL blocks 32 tiles (A split into 2 col-halves).
// No LDS, no barriers (masks pre-packed by p0). Wave = head, 16 rows.
__global__ __launch_bounds__(256) void p2_kernel(
    const unsigned int* __restrict__ mA, const unsigned int* __restrict__ mB,
    const _Float16* __restrict__ vtA, const _Float16* __restrict__ vtB,
    const float* __restrict__ eRowA, const float* __restrict__ eColA,
    const float* __restrict__ eRowB, const float* __restrict__ eColB,
    const float* __restrict__ bu, const float* __restrict__ bn,
    float* __restrict__ numA, float* __restrict__ denA,
    float* __restrict__ out)
{
  const int tid = threadIdx.x;
  const int h = tid >> 6, l = tid & 63;
  const int row16 = l & 15;
  const int cg = (l >> 4) << 3;
  const int bid = blockIdx.x;

  f32x4 acc0 = {0.f,0.f,0.f,0.f}, acc1 = {0.f,0.f,0.f,0.f}, accd = {0.f,0.f,0.f,0.f};
  half8 ones = {(_Float16)1.f, (_Float16)1.f, (_Float16)1.f, (_Float16)1.f,
                (_Float16)1.f, (_Float16)1.f, (_Float16)1.f, (_Float16)1.f};

  const float* ecolH;
  const _Float16* vtb;
  const unsigned int* mT;
  float eq;
  int t0;
  if (bid < 1024) {                      // A-dir: b x rt(64) x half g
    const int b = bid & 7, rest = bid >> 3;
    const int rt = rest & 63, g = rest >> 6;
    eq = eRowA[(size_t)(b * H_ + h) * U_ + rt * 16 + row16];
    ecolH = eColA + (size_t)(b * H_ + h) * N_;
    vtb = vtA + (size_t)(b * H_ + h) * (N_ * HD);
    mT = mA + ((size_t)(b * 64 + rt) * 64) * 16;
    t0 = g * 32;
  } else {                               // B-dir: b x rt(128)
    const int t2 = bid - 1024;
    const int b = t2 & 7, rt = t2 >> 3;
    eq = eRowB[(size_t)(b * H_ + h) * N_ + rt * 16 + row16];
    ecolH = eColB + (size_t)(b * H_ + h) * U_;
    vtb = vtB + (size_t)(b * H_ + h) * (U_ * HD);
    mT = mB + ((size_t)(b * 128 + rt) * 32) * 16;
    t0 = 0;
  }

  #pragma unroll 2
  for (int tt = 0; tt < 32; ++tt) {
    const int t = t0 + tt;
    const int cb = t * 32 + cg;
    unsigned int mb = mT[t * 16 + row16] >> cg;
    float4 e0 = *(const float4*)(ecolH + cb);
    float4 e1 = *(const float4*)(ecolH + cb + 4);
    float ecv[8] = {e0.x, e0.y, e0.z, e0.w, e1.x, e1.y, e1.z, e1.w};
    float wv[8];
    #pragma unroll
    for (int j = 0; j < 8; ++j) {
      float s  = eq + ecv[j];                 // log2e-scaled
      float ls = fmaxf(s, 0.2f * s);          // leaky
      ls = (mb & (1u << j)) ? ls : -1e9f;     // masked -> exp2 underflow to 0
      wv[j] = exp2f(ls);
    }
    union { fp16x2 h2[4]; half8 h8; } uw;
    uw.h2[0] = __builtin_amdgcn_cvt_pkrtz(wv[0], wv[1]);
    uw.h2[1] = __builtin_amdgcn_cvt_pkrtz(wv[2], wv[3]);
    uw.h2[2] = __builtin_amdgcn_cvt_pkrtz(wv[4], wv[5]);
    uw.h2[3] = __builtin_amdgcn_cvt_pkrtz(wv[6], wv[7]);
    half8 w = uw.h8;
    const half8 v0 = *(const half8*)(vtb + t * (HD * 32) + row16 * 32 + cg);
    const half8 v1 = *(const half8*)(vtb + t * (HD * 32) + (row16 + 16) * 32 + cg);
    acc0 = __builtin_amdgcn_mfma_f32_16x16x32_f16(w, v0, acc0, 0, 0, 0);
    acc1 = __builtin_amdgcn_mfma_f32_16x16x32_f16(w, v1, acc1, 0, 0, 0);
    accd = __builtin_amdgcn_mfma_f32_16x16x32_f16(w, ones, accd, 0, 0, 0);
  }

  const int colk = row16;
  const int g4 = (l >> 4) << 2;
  if (bid < 1024) {                      // A-dir: store partials (combined in p3)
    const int b = bid & 7, rest = bid >> 3;
    const int rt = rest & 63, g = rest >> 6;
    #pragma unroll
    for (int q = 0; q < 4; ++q) {
      int orow = rt * 16 + g4 + q;
      size_t o = (((size_t)(g * 8 + b) * H_ + h) * U_ + orow) * 32 + colk;
      numA[o] = acc0[q];
      numA[o + 16] = acc1[q];
      if (colk == 0) denA[((size_t)(g * 8 + b) * H_ + h) * U_ + orow] = accd[q];
    }
  } else {                               // B-dir: fused epilogue direct to out
    const int t2 = bid - 1024;
    const int b = t2 & 7, rt = t2 >> 3;
    #pragma unroll
    for (int q = 0; q < 4; ++q) {
      int orow = rt * 16 + g4 + q;
      size_t o = ((size_t)(b * H_ + h) * N_ + orow) * 32 + colk;
      float den = accd[q];
      float v0 = acc0[q] / den + bn[q * 32 + colk];
      float v1 = acc1[q] / den + bn[q * 32 + colk + 16];
      out[NU + o]      = v0 > 0.f ? v0 : 0.f;
      out[NU + o + 16] = v1 > 0.f ? v1 : 0.f;
    }
  }
}

// ---------------- phase 3: combine A halves, divide, bias, relu ----------------
__global__ __launch_bounds__(256) void p3_kernel(
    const float* __restrict__ numA, const float* __restrict__ denA,
    const float* __restrict__ bu, float* __restrict__ out)
{
  int idx = blockIdx.x * 256 + threadIdx.x;
  float n = numA[idx] + numA[idx + NU];
  int dr = idx >> 5;
  float d = denA[dr] + denA[dr + B_ * H_ * U_];
  float v = n / d + bu[idx & 127];
  out[idx] = v > 0.f ? v : 0.f;
}

extern "C" void kernel_launch(void* const* d_in, const int* in_sizes, int n_in,
                              void* d_out, int out_size, void* d_ws, size_t ws_size,
                              hipStream_t stream) {
  const float* uf  = (const float*)d_in[0];
  const float* nf  = (const float*)d_in[1];
  const int*   adj = (const int*)d_in[2];
  const float* Wu  = (const float*)d_in[3];
  const float* Wn  = (const float*)d_in[4];
  const float* aun = (const float*)d_in[5];
  const float* anu = (const float*)d_in[6];
  const float* bu  = (const float*)d_in[7];
  const float* bn  = (const float*)d_in[8];

  char* ws = (char*)d_ws;
  size_t off = 0;
  _Float16* vtA = (_Float16*)(ws + off); off += (size_t)B_ * H_ * HD * N_ * 2;  // 4 MB
  _Float16* vtB = (_Float16*)(ws + off); off += (size_t)B_ * H_ * HD * U_ * 2;  // 2 MB
  float* eRowA = (float*)(ws + off); off += (size_t)B_ * H_ * U_ * 4;
  float* eColA = (float*)(ws + off); off += (size_t)B_ * H_ * N_ * 4;
  float* eRowB = (float*)(ws + off); off += (size_t)B_ * H_ * N_ * 4;
  float* eColB = (float*)(ws + off); off += (size_t)B_ * H_ * U_ * 4;
  unsigned int* mA = (unsigned int*)(ws + off); off += (size_t)B_ * 64 * 64 * 16 * 4;  // 2 MB
  unsigned int* mB = (unsigned int*)(ws + off); off += (size_t)B_ * 128 * 32 * 16 * 4; // 2 MB
  float* numA = (float*)(ws + off); off += (size_t)2 * NU * 4;                         // 8 MB
  float* denA = (float*)(ws + off); off += (size_t)2 * B_ * H_ * U_ * 4;
  (void)off; (void)ws_size; (void)in_sizes; (void)n_in; (void)out_size;        // ~19.7 MB

  p0_kernel<<<6144, 256, 0, stream>>>(adj, mA, mB);
  p1_kernel<<<512 + 1024, 256, 0, stream>>>(uf, nf, Wu, Wn, aun, anu,
                                            vtA, vtB, eRowA, eColA, eRowB, eColB);
  p2_kernel<<<2048, 256, 0, stream>>>(mA, mB, vtA, vtB, eRowA, eColA,
                                      eRowB, eColB, bu, bn, numA, denA, (float*)d_out);
  p3_kernel<<<NU / 256, 256, 0, stream>>>(numA, denA, bu, (float*)d_out);
}

// Round 14
// 120.061 us; speedup vs baseline: 1.1334x; 1.0183x over previous
//
#include <hip/hip_runtime.h>
#include <hip/hip_bf16.h>

typedef _Float16 half8 __attribute__((ext_vector_type(8)));
typedef __fp16 fp16x2 __attribute__((ext_vector_type(2)));
typedef float f32x4 __attribute__((ext_vector_type(4)));

#define B_ 8
#define U_ 1024
#define N_ 2048
#define DIN 128
#define H_ 4
#define HD 32
#define S_ 3072
#define LOG2E 1.44269504f
#define NU (B_ * U_ * 128)            // 1048576

// ---------------- phase 0: adjacency -> tiled global bitmasks (unchanged) ----------------
__global__ __launch_bounds__(256) void p0_kernel(
    const int* __restrict__ adj,
    unsigned int* __restrict__ mA, unsigned int* __restrict__ mB)
{
  const int task = blockIdx.x * 4 + (threadIdx.x >> 6);
  const int l = threadIdx.x & 63;
  const int* rowp;
  unsigned int* mOut;
  int iters;
  if (task < 8192) {                    // A-dir: user rows x news cols
    int b = task >> 10, r = task & 1023;
    rowp = adj + ((size_t)b * S_ + r) * S_ + U_;
    iters = 32;
    mOut = mA + ((size_t)(b * 64 + (r >> 4)) * 64) * 16 + (r & 15);
  } else {                              // B-dir: news rows x user cols
    int t2 = task - 8192;
    int b = t2 >> 11, r = t2 & 2047;
    rowp = adj + ((size_t)b * S_ + U_ + r) * S_;
    iters = 16;
    mOut = mB + ((size_t)(b * 128 + (r >> 4)) * 32) * 16 + (r & 15);
  }
  #pragma unroll 4
  for (int it = 0; it < iters; ++it) {
    int av = rowp[it * 64 + l];
    unsigned long long m = __ballot(av != 0);
    if (l == 0) {
      mOut[(2 * it) * 16]     = (unsigned int)m;
      mOut[(2 * it + 1) * 16] = (unsigned int)(m >> 32);
    }
  }
}

// ---------------- phase 1: projections + raw e + tiled f16 V (unchanged) ----------------
__global__ __launch_bounds__(256) void p1_kernel(
    const float* __restrict__ uf, const float* __restrict__ nf,
    const float* __restrict__ Wu, const float* __restrict__ Wn,
    const float* __restrict__ a_un, const float* __restrict__ a_nu,
    _Float16* __restrict__ vtA, _Float16* __restrict__ vtB,
    float* __restrict__ eRowA, float* __restrict__ eColA,
    float* __restrict__ eRowB, float* __restrict__ eColB)
{
  __shared__ float fs[64][132];
  __shared__ float WsT[32][132];
  __shared__ float qt[32][65];
  __shared__ float aAs[32], aBs[32];

  const int bid = blockIdx.x;
  const int tid = threadIdx.x;

  int b, rt, R, h;
  const float *feat, *W;
  _Float16* vt;
  float *eA, *eB;
  int aAoff, aBoff;
  const float *avA, *avB;
  if (bid < 512) {                       // users: 8b x 16rt x 4h
    h = bid & 3; int t2 = bid >> 2; b = t2 >> 4; rt = t2 & 15; R = U_;
    feat = uf; W = Wu; vt = vtB;
    eA = eRowA; eB = eColB;
    avA = a_un; aAoff = 0;  avB = a_nu; aBoff = HD;
  } else {                               // news: 8b x 32rt x 4h
    int t3 = bid - 512;
    h = t3 & 3; int t2 = t3 >> 2; b = t2 >> 5; rt = t2 & 31; R = N_;
    feat = nf; W = Wn; vt = vtA;
    eA = eColA; eB = eRowB;
    avA = a_un; aAoff = HD; avB = a_nu; aBoff = 0;
  }
  const int r0 = rt * 64;

  const float4* feat4 = (const float4*)(feat + ((size_t)b * R + r0) * DIN);
  #pragma unroll
  for (int i = 0; i < 8; ++i) {
    int f4 = tid + 256 * i;
    int row = f4 >> 5, c4 = f4 & 31;
    *(float4*)&fs[row][c4 * 4] = feat4[row * 32 + c4];
  }
  {
    const float4* W4 = (const float4*)(W + (size_t)h * DIN * HD);
    #pragma unroll
    for (int i = 0; i < 4; ++i) {
      int f4 = tid + 256 * i;
      int d = f4 >> 3, kc = f4 & 7;
      float4 v = W4[f4];
      WsT[kc * 4 + 0][d] = v.x;
      WsT[kc * 4 + 1][d] = v.y;
      WsT[kc * 4 + 2][d] = v.z;
      WsT[kc * 4 + 3][d] = v.w;
    }
    if (tid < 32) {
      aAs[tid] = avA[h * 64 + aAoff + tid];
      aBs[tid] = avB[h * 64 + aBoff + tid];
    }
  }
  __syncthreads();

  const int kk = tid & 15, uu = tid >> 4;
  {
    float acc0[4] = {0.f, 0.f, 0.f, 0.f}, acc1[4] = {0.f, 0.f, 0.f, 0.f};
    #pragma unroll 8
    for (int d = 0; d < DIN; d += 4) {
      float4 w0 = *(const float4*)&WsT[kk][d];
      float4 w1 = *(const float4*)&WsT[kk + 16][d];
      #pragma unroll
      for (int i = 0; i < 4; ++i) {
        float4 fv = *(const float4*)&fs[uu + 16 * i][d];
        acc0[i] = fmaf(fv.x, w0.x, acc0[i]); acc0[i] = fmaf(fv.y, w0.y, acc0[i]);
        acc0[i] = fmaf(fv.z, w0.z, acc0[i]); acc0[i] = fmaf(fv.w, w0.w, acc0[i]);
        acc1[i] = fmaf(fv.x, w1.x, acc1[i]); acc1[i] = fmaf(fv.y, w1.y, acc1[i]);
        acc1[i] = fmaf(fv.z, w1.z, acc1[i]); acc1[i] = fmaf(fv.w, w1.w, acc1[i]);
      }
    }
    #pragma unroll
    for (int i = 0; i < 4; ++i) {
      qt[kk][uu + 16 * i] = acc0[i];
      qt[kk + 16][uu + 16 * i] = acc1[i];
    }
  }
  __syncthreads();

  const int u2 = tid & 63, part = tid >> 6;
  {
    size_t vtbase = (size_t)(b * H_ + h) * (R * HD)
                  + (size_t)((r0 >> 5) + (u2 >> 5)) * (HD * 32) + (u2 & 31);
    #pragma unroll
    for (int jj = 0; jj < 8; ++jj) {
      int krow = part * 8 + jj;
      vt[vtbase + krow * 32] = (_Float16)qt[krow][u2];
    }
  }
  if (part < 2) {
    float a_ = 0.f;
    const float* av = (part == 0) ? aAs : aBs;
    #pragma unroll
    for (int k2 = 0; k2 < HD; ++k2)
      a_ = fmaf(qt[k2][u2], av[k2], a_);
    float* e = (part == 0) ? eA : eB;
    e[(size_t)(b * H_ + h) * R + r0 + u2] = a_ * LOG2E;  // raw, log2e-scaled
  }
}

// ---------------- phase 2: LDS-shared double-buffered masked-softmax GEMM ----------------
// Block = (b, h, 64 rows): all 4 waves SAME head -> V tile (2KB) shared via LDS.
// Per tile: wave0 prefetches vt(t+1) to regs; all compute t from LDS; bar;
// wave0 ds_writes vt(t+1); bar. e panel (4KB) + masks (8KB) prestaged in LDS.
// vt LDS rows padded to 80B -> b128 reads ~4-way instead of 8-way conflicts.
__global__ __launch_bounds__(256, 6) void p2_kernel(
    const unsigned int* __restrict__ mA, const unsigned int* __restrict__ mB,
    const _Float16* __restrict__ vtA, const _Float16* __restrict__ vtB,
    const float* __restrict__ eRowA, const float* __restrict__ eColA,
    const float* __restrict__ eRowB, const float* __restrict__ eColB,
    const float* __restrict__ bn,
    float* __restrict__ numA, float* __restrict__ denA,
    float* __restrict__ out)
{
  __shared__ float eS[1024];                   // 4KB e panel (local cols 0..1023)
  __shared__ unsigned int mS[4][32][16];       // 8KB masks [wave][t][r16]
  __shared__ char vbufc[2][32 * 80];           // 2x2.5KB vt dbuf, 80B row stride

  const int tid = threadIdx.x;
  const int w = tid >> 6, l = tid & 63;
  const int row16 = l & 15;
  const int cg = (l >> 4) << 3;                // K offset 0,8,16,24

  const int bid = blockIdx.x;
  int b, h, rg, t0;
  const _Float16* vtH;
  const float *ecolH, *erowH;
  const unsigned int* mRow;
  const bool isA = (bid < 1024);
  if (isA) {                                   // 8b x 4h x 16rg x 2g
    b = bid & 7; int r1 = bid >> 3; h = r1 & 3; int r2 = r1 >> 2;
    rg = r2 & 15; int g = r2 >> 4;
    t0 = g * 32;
    vtH = vtA + (size_t)(b * H_ + h) * (N_ * HD);
    ecolH = eColA + (size_t)(b * H_ + h) * N_;
    erowH = eRowA + (size_t)(b * H_ + h) * U_;
    mRow = mA + ((size_t)(b * 64 + rg * 4 + w) * 64 + t0) * 16;
  } else {                                     // 8b x 4h x 32rg
    int t2 = bid - 1024;
    b = t2 & 7; int r1 = t2 >> 3; h = r1 & 3; rg = r1 >> 2;
    t0 = 0;
    vtH = vtB + (size_t)(b * H_ + h) * (U_ * HD);
    ecolH = eColB + (size_t)(b * H_ + h) * U_;
    erowH = eRowB + (size_t)(b * H_ + h) * N_;
    mRow = mB + ((size_t)(b * 128 + rg * 4 + w) * 32) * 16;
  }

  // ---- prologue: stage e panel, mask chunks, vt tile t0 ----
  unsigned int* mf = &mS[0][0][0];
  {
    float4 ev = *(const float4*)(ecolH + t0 * 32 + tid * 4);
    *(float4*)&eS[tid * 4] = ev;
    int4 m0 = *(const int4*)(mRow + l * 8);
    int4 m1 = *(const int4*)(mRow + l * 8 + 4);
    *(int4*)(mf + w * 512 + l * 8) = m0;
    *(int4*)(mf + w * 512 + l * 8 + 4) = m1;
  }
  const int srow = l >> 2, sch = l & 3;
  const int soff0 = srow * 80 + sch * 16;
  const int soff1 = (srow + 16) * 80 + sch * 16;
  if (w == 0) {
    const char* gsrc = (const char*)(vtH + (size_t)t0 * 1024);
    int4 pa = *(const int4*)(gsrc + l * 16);
    int4 pb = *(const int4*)(gsrc + 1024 + l * 16);
    *(int4*)&vbufc[0][soff0] = pa;
    *(int4*)&vbufc[0][soff1] = pb;
  }
  __syncthreads();

  const float eq = erowH[rg * 64 + w * 16 + row16];

  f32x4 acc0 = {0.f,0.f,0.f,0.f}, acc1 = {0.f,0.f,0.f,0.f}, accd = {0.f,0.f,0.f,0.f};
  half8 ones = {(_Float16)1.f, (_Float16)1.f, (_Float16)1.f, (_Float16)1.f,
                (_Float16)1.f, (_Float16)1.f, (_Float16)1.f, (_Float16)1.f};

  #pragma unroll 2
  for (int t = 0; t < 32; ++t) {
    const bool more = (t < 31);
    int4 pa, pb;
    if (w == 0 && more) {                      // prefetch vt(t+1) to regs
      const char* gsrc = (const char*)(vtH + (size_t)(t0 + t + 1) * 1024);
      pa = *(const int4*)(gsrc + l * 16);
      pb = *(const int4*)(gsrc + 1024 + l * 16);
    }
    // ---- compute tile t from LDS ----
    unsigned int mb = mf[w * 512 + t * 16 + row16] >> cg;
    float4 e0 = *(const float4*)&eS[t * 32 + cg];
    float4 e1 = *(const float4*)&eS[t * 32 + cg + 4];
    float ecv[8] = {e0.x, e0.y, e0.z, e0.w, e1.x, e1.y, e1.z, e1.w};
    float wv[8];
    #pragma unroll
    for (int j = 0; j < 8; ++j) {
      float s  = eq + ecv[j];                 // log2e-scaled
      float ls = fmaxf(s, 0.2f * s);          // leaky
      ls = (mb & (1u << j)) ? ls : -1e9f;     // masked -> exp2 underflow to 0
      wv[j] = exp2f(ls);
    }
    union { fp16x2 h2[4]; half8 h8; } uw;
    uw.h2[0] = __builtin_amdgcn_cvt_pkrtz(wv[0], wv[1]);
    uw.h2[1] = __builtin_amdgcn_cvt_pkrtz(wv[2], wv[3]);
    uw.h2[2] = __builtin_amdgcn_cvt_pkrtz(wv[4], wv[5]);
    uw.h2[3] = __builtin_amdgcn_cvt_pkrtz(wv[6], wv[7]);
    half8 wgt = uw.h8;
    const char* vb = vbufc[t & 1];
    half8 v0 = *(const half8*)(vb + row16 * 80 + (cg >> 3) * 16);
    half8 v1 = *(const half8*)(vb + (row16 + 16) * 80 + (cg >> 3) * 16);
    acc0 = __builtin_amdgcn_mfma_f32_16x16x32_f16(wgt, v0, acc0, 0, 0, 0);
    acc1 = __builtin_amdgcn_mfma_f32_16x16x32_f16(wgt, v1, acc1, 0, 0, 0);
    accd = __builtin_amdgcn_mfma_f32_16x16x32_f16(wgt, ones, accd, 0, 0, 0);
    if (more) {
      __syncthreads();                         // all waves done reading vbuf[(t+1)&1]
      if (w == 0) {
        *(int4*)&vbufc[(t + 1) & 1][soff0] = pa;
        *(int4*)&vbufc[(t + 1) & 1][soff1] = pb;
      }
      __syncthreads();                         // vt(t+1) visible to all
    }
  }

  // ---- epilogue ----
  const int colk = row16;
  const int g4 = (l >> 4) << 2;
  if (isA) {                                   // partials, combined in p3
    const int g = t0 >> 5;
    #pragma unroll
    for (int q = 0; q < 4; ++q) {
      int orow = rg * 64 + w * 16 + g4 + q;
      size_t o = (((size_t)(g * 8 + b) * H_ + h) * U_ + orow) * 32 + colk;
      numA[o] = acc0[q];
      numA[o + 16] = acc1[q];
      if (colk == 0) denA[((size_t)(g * 8 + b) * H_ + h) * U_ + orow] = accd[q];
    }
  } else {                                     // fused epilogue direct to out
    #pragma unroll
    for (int q = 0; q < 4; ++q) {
      int orow = rg * 64 + w * 16 + g4 + q;
      size_t o = ((size_t)(b * H_ + h) * N_ + orow) * 32 + colk;
      float den = accd[q];
      float v0 = acc0[q] / den + bn[q * 32 + colk];
      float v1 = acc1[q] / den + bn[q * 32 + colk + 16];
      out[NU + o]      = v0 > 0.f ? v0 : 0.f;
      out[NU + o + 16] = v1 > 0.f ? v1 : 0.f;
    }
  }
}

// ---------------- phase 3: combine A halves, divide, bias, relu (unchanged) ----------------
__global__ __launch_bounds__(256) void p3_kernel(
    const float* __restrict__ numA, const float* __restrict__ denA,
    const float* __restrict__ bu, float* __restrict__ out)
{
  int idx = blockIdx.x * 256 + threadIdx.x;
  float n = numA[idx] + numA[idx + NU];
  int dr = idx >> 5;
  float d = denA[dr] + denA[dr + B_ * H_ * U_];
  float v = n / d + bu[idx & 127];
  out[idx] = v > 0.f ? v : 0.f;
}

extern "C" void kernel_launch(void* const* d_in, const int* in_sizes, int n_in,
                              void* d_out, int out_size, void* d_ws, size_t ws_size,
                              hipStream_t stream) {
  const float* uf  = (const float*)d_in[0];
  const float* nf  = (const float*)d_in[1];
  const int*   adj = (const int*)d_in[2];
  const float* Wu  = (const float*)d_in[3];
  const float* Wn  = (const float*)d_in[4];
  const float* aun = (const float*)d_in[5];
  const float* anu = (const float*)d_in[6];
  const float* bu  = (const float*)d_in[7];
  const float* bn  = (const float*)d_in[8];

  char* ws = (char*)d_ws;
  size_t off = 0;
  _Float16* vtA = (_Float16*)(ws + off); off += (size_t)B_ * H_ * HD * N_ * 2;  // 4 MB
  _Float16* vtB = (_Float16*)(ws + off); off += (size_t)B_ * H_ * HD * U_ * 2;  // 2 MB
  float* eRowA = (float*)(ws + off); off += (size_t)B_ * H_ * U_ * 4;
  float* eColA = (float*)(ws + off); off += (size_t)B_ * H_ * N_ * 4;
  float* eRowB = (float*)(ws + off); off += (size_t)B_ * H_ * N_ * 4;
  float* eColB = (float*)(ws + off); off += (size_t)B_ * H_ * U_ * 4;
  unsigned int* mA = (unsigned int*)(ws + off); off += (size_t)B_ * 64 * 64 * 16 * 4;  // 2 MB
  unsigned int* mB = (unsigned int*)(ws + off); off += (size_t)B_ * 128 * 32 * 16 * 4; // 2 MB
  float* numA = (float*)(ws + off); off += (size_t)2 * NU * 4;                         // 8 MB
  float* denA = (float*)(ws + off); off += (size_t)2 * B_ * H_ * U_ * 4;
  (void)off; (void)ws_size; (void)in_sizes; (void)n_in; (void)out_size;        // ~19.7 MB

  p0_kernel<<<6144, 256, 0, stream>>>(adj, mA, mB);
  p1_kernel<<<512 + 1024, 256, 0, stream>>>(uf, nf, Wu, Wn, aun, anu,
                                            vtA, vtB, eRowA, eColA, eRowB, eColB);
  p2_kernel<<<2048, 256, 0, stream>>>(mA, mB, vtA, vtB, eRowA, eColA,
                                      eRowB, eColB, bn, numA, denA, (float*)d_out);
  p3_kernel<<<NU / 256, 256, 0, stream>>>(numA, denA, bu, (float*)d_out);
}